// Round 7
// baseline (833.851 us; speedup 1.0000x reference)
//
#include <hip/hip_runtime.h>
#include <hip/hip_bf16.h>

typedef __bf16 b8v __attribute__((ext_vector_type(8)));
typedef float  f4v __attribute__((ext_vector_type(4)));
typedef unsigned long long ull;

#define AS3(p)  ((__attribute__((address_space(3))) void*)(p))
#define AS1C(p) ((const __attribute__((address_space(1))) void*)(p))
#define MFMA16(a, b, c) __builtin_amdgcn_mfma_f32_16x16x32_bf16((a), (b), (c), 0, 0, 0)

// ============================================================================
// gemm256: C[M,N] = A[M,K] @ Bt[N,K]^T  (bf16 in/out, fp32 acc)
// m201 template cadence, R7: 256x256 tile, BK=64, 512 thr = 8 waves (2Mx4N),
// per-wave 128x64.  LDS [dbuf2][half2][128x64] x {A,B} = 128 KiB.
// Reads per phase 8/4/8/4 (phD pre-reads next tile's bfL from other buffer);
// stages: phA = Ah0+Ah1(t+1) [4 loads], phB = Bh0+Bh1(t+1) [4 loads].
// Counted waits BEFORE the reads that need them (each vmcnt precedes a
// barrier for cross-wave visibility):
//   phB: vmcnt(4)  -> retires Bh1(t)    (issued t-1 phB, ~4 phases cover)
//   phD: vmcnt(2)  -> retires Bh0(t+1)+Ah(t+1) (issued t phA/B, ~2 phases)
// Never vmcnt(0) except the tail tile.  Phase: {vmcnt?; barrier; ds_reads;
// stage; barrier; lgkmcnt(0)+sched_barrier; setprio(1); 16 MFMA (kh0 sweep
// then kh1); setprio(0)}.
// WAR: Bs[t&1] last read t phB, overwritten t+1 phB; As[t&1] last read t phC,
// overwritten t+1 phA - all sealed by >=2 barriers.
// Swizzle (R6-verified): chunk c of row r holds global chunk c^(r&7) via
// pre-swizzled global source (linear LDS dest); reads apply same XOR.
// EPI: 0 none, 1 relu, 2 bias+gelu (bias by bz&1).  Output bf16.
// Bt batch offset = (z>>3)*sBg + (z&7)*sBb.
// ============================================================================
template<int EPI>
__global__ __launch_bounds__(512, 2) void gemm256(
    const __hip_bfloat16* __restrict__ A,  long long sA,
    const __hip_bfloat16* __restrict__ Bt, long long sBg, long long sBb, int ldB,
    __hip_bfloat16* __restrict__ C, long long sC, int ldC,
    const float* __restrict__ bias0, const float* __restrict__ bias1, int K)
{
  const int bz = blockIdx.z;
  A  += (long long)bz * sA;
  Bt += (long long)(bz >> 3) * sBg + (long long)(bz & 7) * sBb;
  const float* __restrict__ bias = (bz & 1) ? bias1 : bias0;

  __shared__ __hip_bfloat16 As[2][2][8192];   // [dbuf][half][128 rows x 64 k]
  __shared__ __hip_bfloat16 Bs[2][2][8192];

  const int tid  = threadIdx.x;
  const int lane = tid & 63;
  const int wave = tid >> 6;
  const int wr = wave >> 2;          // 0..1 : M half (128 rows)
  const int wc = wave & 3;           // 0..3 : N quarter (64 cols)
  const int lm = lane & 15;
  const int kq = lane >> 4;

  const long long m0 = (long long)blockIdx.x * 256;
  const long long n0 = (long long)blockIdx.y * 256;

  // staging: thread -> (row sr, chunk sc); global chunk pre-swizzled sc^(sr&7)
  const int sr  = tid >> 3;                    // 0..63
  const int sc  = tid & 7;
  const int gch = sc ^ (sr & 7);
  const int ldsE = tid * 8;                    // element offset of 16B slot

  auto stageA = [&](int d, int kt) {           // both A halves: 4 loads
    const __hip_bfloat16* s0 = A + (m0 + sr) * (long long)K + (long long)kt * 64 + gch * 8;
    __builtin_amdgcn_global_load_lds(AS1C(s0),              AS3(&As[d][0][ldsE]),        16, 0, 0);
    __builtin_amdgcn_global_load_lds(AS1C(s0 + 64LL * K),   AS3(&As[d][0][4096 + ldsE]), 16, 0, 0);
    __builtin_amdgcn_global_load_lds(AS1C(s0 + 128LL * K),  AS3(&As[d][1][ldsE]),        16, 0, 0);
    __builtin_amdgcn_global_load_lds(AS1C(s0 + 192LL * K),  AS3(&As[d][1][4096 + ldsE]), 16, 0, 0);
  };
  auto stageB = [&](int d, int kt) {           // both B halves: 4 loads
    const __hip_bfloat16* s0 = Bt + (n0 + sr) * (long long)ldB + (long long)kt * 64 + gch * 8;
    __builtin_amdgcn_global_load_lds(AS1C(s0),               AS3(&Bs[d][0][ldsE]),        16, 0, 0);
    __builtin_amdgcn_global_load_lds(AS1C(s0 + 64LL * ldB),  AS3(&Bs[d][0][4096 + ldsE]), 16, 0, 0);
    __builtin_amdgcn_global_load_lds(AS1C(s0 + 128LL * ldB), AS3(&Bs[d][1][ldsE]),        16, 0, 0);
    __builtin_amdgcn_global_load_lds(AS1C(s0 + 192LL * ldB), AS3(&Bs[d][1][4096 + ldsE]), 16, 0, 0);
  };

  const int NT = K >> 6;

  f4v acc[8][4];
  const f4v fz = {0.0f, 0.0f, 0.0f, 0.0f};
#pragma unroll
  for (int i = 0; i < 8; i++)
#pragma unroll
    for (int j = 0; j < 4; j++) acc[i][j] = fz;

  // lane read constants: elem off = frag*1024 + lm*64 + ((kh*4+kq)^(lm&7))*8
  const int rb  = lm * 64;
  const int cs0 = ((kq)     ^ (lm & 7)) * 8;   // kh=0
  const int cs1 = ((4 + kq) ^ (lm & 7)) * 8;   // kh=1

  // prologue: stage tile0 (A then B, 8 loads); retire through Bh0(0); read bfL(0)
  stageA(0, 0); stageB(0, 0);
  asm volatile("s_waitcnt vmcnt(2)" ::: "memory");
  __builtin_amdgcn_s_barrier();

  b8v bfL[4];                                   // loop-carried: B frags f0-1
  {
    const __hip_bfloat16* Bb0 = &Bs[0][wc >> 1][(wc & 1) * 4096];
#pragma unroll
    for (int f = 0; f < 2; f++) {
      bfL[f * 2]     = *(const b8v*)(Bb0 + f * 1024 + rb + cs0);
      bfL[f * 2 + 1] = *(const b8v*)(Bb0 + f * 1024 + rb + cs1);
    }
  }

  for (int kt = 0; kt < NT; ++kt) {
    const int d = kt & 1, dn = d ^ 1;
    const __hip_bfloat16* Ab  = &As[d][wr][0];
    const __hip_bfloat16* Bb  = &Bs[d][wc >> 1][(wc & 1) * 4096];
    const __hip_bfloat16* Bbn = &Bs[dn][wc >> 1][(wc & 1) * 4096];
    const bool st1 = (kt + 1 < NT);
    b8v afL[8], afH[8], bfH[4];

    // ---- phase A: reads afL(8); stage Ah0+Ah1(t+1); MFMA (i0-3 x j0-1) ----
    __builtin_amdgcn_s_barrier();
#pragma unroll
    for (int f = 0; f < 4; f++) {
      afL[f * 2]     = *(const b8v*)(Ab + f * 1024 + rb + cs0);
      afL[f * 2 + 1] = *(const b8v*)(Ab + f * 1024 + rb + cs1);
    }
    if (st1) stageA(dn, kt + 1);
    __builtin_amdgcn_s_barrier();
    asm volatile("s_waitcnt lgkmcnt(0)" ::: "memory");
    __builtin_amdgcn_sched_barrier(0);
    __builtin_amdgcn_s_setprio(1);
#pragma unroll
    for (int i = 0; i < 4; i++)
#pragma unroll
      for (int j = 0; j < 2; j++) acc[i][j] = MFMA16(bfL[j * 2], afL[i * 2], acc[i][j]);
#pragma unroll
    for (int i = 0; i < 4; i++)
#pragma unroll
      for (int j = 0; j < 2; j++) acc[i][j] = MFMA16(bfL[j * 2 + 1], afL[i * 2 + 1], acc[i][j]);
    __builtin_amdgcn_s_setprio(0);

    // ---- phase B: vmcnt(4) [Bh1(t) resident]; reads bfH(4); stage B(t+1);
    //      MFMA (i0-3 x j2-3) ----
    if (st1) asm volatile("s_waitcnt vmcnt(4)" ::: "memory");
    else     asm volatile("s_waitcnt vmcnt(0)" ::: "memory");
    __builtin_amdgcn_s_barrier();
#pragma unroll
    for (int f = 0; f < 2; f++) {
      bfH[f * 2]     = *(const b8v*)(Bb + (2 + f) * 1024 + rb + cs0);
      bfH[f * 2 + 1] = *(const b8v*)(Bb + (2 + f) * 1024 + rb + cs1);
    }
    if (st1) stageB(dn, kt + 1);
    __builtin_amdgcn_s_barrier();
    asm volatile("s_waitcnt lgkmcnt(0)" ::: "memory");
    __builtin_amdgcn_sched_barrier(0);
    __builtin_amdgcn_s_setprio(1);
#pragma unroll
    for (int i = 0; i < 4; i++)
#pragma unroll
      for (int j = 0; j < 2; j++) acc[i][2 + j] = MFMA16(bfH[j * 2], afL[i * 2], acc[i][2 + j]);
#pragma unroll
    for (int i = 0; i < 4; i++)
#pragma unroll
      for (int j = 0; j < 2; j++) acc[i][2 + j] = MFMA16(bfH[j * 2 + 1], afL[i * 2 + 1], acc[i][2 + j]);
    __builtin_amdgcn_s_setprio(0);

    // ---- phase C: reads afH(8); MFMA (i4-7 x j0-1) ----
    __builtin_amdgcn_s_barrier();
#pragma unroll
    for (int f = 0; f < 4; f++) {
      afH[f * 2]     = *(const b8v*)(Ab + (4 + f) * 1024 + rb + cs0);
      afH[f * 2 + 1] = *(const b8v*)(Ab + (4 + f) * 1024 + rb + cs1);
    }
    __builtin_amdgcn_s_barrier();
    asm volatile("s_waitcnt lgkmcnt(0)" ::: "memory");
    __builtin_amdgcn_sched_barrier(0);
    __builtin_amdgcn_s_setprio(1);
#pragma unroll
    for (int i = 0; i < 4; i++)
#pragma unroll
      for (int j = 0; j < 2; j++) acc[4 + i][j] = MFMA16(bfL[j * 2], afH[i * 2], acc[4 + i][j]);
#pragma unroll
    for (int i = 0; i < 4; i++)
#pragma unroll
      for (int j = 0; j < 2; j++) acc[4 + i][j] = MFMA16(bfL[j * 2 + 1], afH[i * 2 + 1], acc[4 + i][j]);
    __builtin_amdgcn_s_setprio(0);

    // ---- phase D: vmcnt(2) [Bh0(t+1)+Ah(t+1) resident]; reads bfL(t+1);
    //      MFMA (i4-7 x j2-3) ----
    if (st1) asm volatile("s_waitcnt vmcnt(2)" ::: "memory");
    __builtin_amdgcn_s_barrier();
    if (st1) {
#pragma unroll
      for (int f = 0; f < 2; f++) {
        bfL[f * 2]     = *(const b8v*)(Bbn + f * 1024 + rb + cs0);
        bfL[f * 2 + 1] = *(const b8v*)(Bbn + f * 1024 + rb + cs1);
      }
    }
    __builtin_amdgcn_s_barrier();
    asm volatile("s_waitcnt lgkmcnt(0)" ::: "memory");
    __builtin_amdgcn_sched_barrier(0);
    __builtin_amdgcn_s_setprio(1);
#pragma unroll
    for (int i = 0; i < 4; i++)
#pragma unroll
      for (int j = 0; j < 2; j++) acc[4 + i][2 + j] = MFMA16(bfH[j * 2], afH[i * 2], acc[4 + i][2 + j]);
#pragma unroll
    for (int i = 0; i < 4; i++)
#pragma unroll
      for (int j = 0; j < 2; j++) acc[4 + i][2 + j] = MFMA16(bfH[j * 2 + 1], afH[i * 2 + 1], acc[4 + i][2 + j]);
    __builtin_amdgcn_s_setprio(0);
  }

  // ---- epilogue: lane holds rows m0+wr*128+i*16+lm, cols n0+wc*64+j*16+kq*4 ----
#pragma unroll
  for (int i = 0; i < 8; i++) {
    const long long row = m0 + wr * 128 + i * 16 + lm;
#pragma unroll
    for (int j = 0; j < 4; j++) {
      const int colb = (int)n0 + wc * 64 + j * 16 + kq * 4;
      float v[4];
#pragma unroll
      for (int rg = 0; rg < 4; rg++) v[rg] = acc[i][j][rg];
      if constexpr (EPI == 1) {
#pragma unroll
        for (int rg = 0; rg < 4; rg++) v[rg] = fmaxf(v[rg], 0.0f);
      }
      if constexpr (EPI == 2) {
        const float4 b4 = *(const float4*)(bias + colb);
        const float* bb = (const float*)&b4;
#pragma unroll
        for (int rg = 0; rg < 4; rg++) {
          float x = v[rg] + bb[rg];
          v[rg] = 0.5f * x * (1.0f + erff(x * 0.70710678118654752f));
        }
      }
      union { __hip_bfloat16 h[4]; ull u; } P;
#pragma unroll
      for (int rg = 0; rg < 4; rg++) P.h[rg] = __float2bfloat16(v[rg]);
      *(ull*)(C + (long long)bz * sC + row * (long long)ldC + colb) = P.u;
    }
  }
}

// ============================================================================
// OLD 128x128 GEMM — retained for the gate GEMM (EPI=3).  Verified baseline.
// ============================================================================
template<int EPI, int OBF, int ORIENT, int MP>
__global__ __launch_bounds__(256) void gemm_bt(
    const __hip_bfloat16* __restrict__ A,  long long sA,
    const __hip_bfloat16* __restrict__ Bt, long long sBg, long long sBb, int ldB,
    void* __restrict__ Cv, long long sC, int ldC,
    const float* __restrict__ bias0, const float* __restrict__ bias1,
    const __hip_bfloat16* __restrict__ gcat, int K)
{
  const int bz = blockIdx.z;
  A  += (long long)bz * sA;
  Bt += (long long)(bz >> 3) * sBg + (long long)(bz & 7) * sBb;
  const float* __restrict__ bias = (bz & 1) ? bias1 : bias0;

  __shared__ __hip_bfloat16 As[128 * 32];
  __shared__ __hip_bfloat16 Bs[128 * 32];

  const int tid  = threadIdx.x;
  const int lane = tid & 63;
  const int wave = tid >> 6;

  const long long mBase = (long long)blockIdx.x * (MP * 128);
  const long long n0    = (long long)blockIdx.y * 128;

  const int r  = tid >> 2;
  const int kc = (tid & 3) ^ ((r >> 2) & 3);
  const __hip_bfloat16* aRow = A  + (mBase + r) * (long long)K   + kc * 8;
  const __hip_bfloat16* bRow = Bt + (n0 + r)    * (long long)ldB + kc * 8;

  const int wm = (wave & 1) * 64;
  const int wn = (wave >> 1) * 64;
  const int lm = lane & 15;
  const int kq = lane >> 4;

  const int sw   = (lm >> 2) & 3;
  const int aOff = (wm + lm) * 32 + (kq ^ sw) * 8;
  const int bOff = (wn + lm) * 32 + (kq ^ sw) * 8;

  auto stage = [&](long long aoff, int k0) {
    const __hip_bfloat16* a = aRow + aoff + k0;
    const __hip_bfloat16* b = bRow + k0;
    __builtin_amdgcn_global_load_lds(AS1C(a),              AS3(As + tid * 8),        16, 0, 0);
    __builtin_amdgcn_global_load_lds(AS1C(a + 64LL * K),   AS3(As + 2048 + tid * 8), 16, 0, 0);
    __builtin_amdgcn_global_load_lds(AS1C(b),              AS3(Bs + tid * 8),        16, 0, 0);
    __builtin_amdgcn_global_load_lds(AS1C(b + 64LL * ldB), AS3(Bs + 2048 + tid * 8), 16, 0, 0);
  };

  stage(0, 0);

  const f4v fzero = {0.0f, 0.0f, 0.0f, 0.0f};
  char* Cb = (char*)Cv;

  for (int p = 0; p < MP; ++p) {
    const long long aoff = (long long)p * 128 * K;

    f4v acc[4][4];
#pragma unroll
    for (int i = 0; i < 4; i++)
#pragma unroll
      for (int j = 0; j < 4; j++) acc[i][j] = fzero;

    for (int k0 = 0; k0 < K; k0 += 32) {
      __syncthreads();

      b8v af[4], bf[4];
#pragma unroll
      for (int i = 0; i < 4; i++) af[i] = *(const b8v*)(As + aOff + i * 16 * 32);
#pragma unroll
      for (int j = 0; j < 4; j++) bf[j] = *(const b8v*)(Bs + bOff + j * 16 * 32);

      __syncthreads();

      if (k0 + 32 < K)            stage(aoff, k0 + 32);
      else if (MP > 1 && p + 1 < MP) stage(aoff + 128LL * K, 0);

#pragma unroll
      for (int i = 0; i < 4; i++)
#pragma unroll
        for (int j = 0; j < 4; j++) {
          if constexpr (ORIENT == 0)
            acc[i][j] = __builtin_amdgcn_mfma_f32_16x16x32_bf16(bf[j], af[i], acc[i][j], 0, 0, 0);
          else
            acc[i][j] = __builtin_amdgcn_mfma_f32_16x16x32_bf16(af[i], bf[j], acc[i][j], 0, 0, 0);
        }
    }

    const long long m0 = mBase + (long long)p * 128;
#pragma unroll
    for (int i = 0; i < 4; i++) {
#pragma unroll
      for (int j = 0; j < 4; j++) {
        float v[4];
#pragma unroll
        for (int rg = 0; rg < 4; rg++) v[rg] = acc[i][j][rg];

        if constexpr (ORIENT == 0) {
          const long long row  = m0 + wm + i * 16 + lm;
          const int       colb = (int)n0 + wn + j * 16 + kq * 4;
          if constexpr (EPI == 1) {
#pragma unroll
            for (int rg = 0; rg < 4; rg++) v[rg] = fmaxf(v[rg], 0.0f);
          }
          if constexpr (EPI == 2) {
            const float4 b4 = *(const float4*)(bias + colb);
            const float* bb = (const float*)&b4;
#pragma unroll
            for (int rg = 0; rg < 4; rg++) {
              float x = v[rg] + bb[rg];
              v[rg] = 0.5f * x * (1.0f + erff(x * 0.70710678118654752f));
            }
          }
          const long long base = bz * sC + row * (long long)ldC + colb;
          if constexpr (EPI == 3) {
            const float4 b4 = *(const float4*)(bias0 + colb);
            const float* bb = (const float*)&b4;
            union { __hip_bfloat16 h[4]; ull u; } g1, g2;
            g1.u = *(const ull*)(gcat + row * 1536 + colb);
            g2.u = *(const ull*)(gcat + row * 1536 + 768 + colb);
            float o[4];
#pragma unroll
            for (int rg = 0; rg < 4; rg++) {
              const float s = 1.0f / (1.0f + expf(-(v[rg] + bb[rg])));
              o[rg] = s * __bfloat162float(g1.h[rg]) +
                      (1.0f - s) * __bfloat162float(g2.h[rg]);
            }
            *(float4*)(Cb + base * 4) = *(const float4*)o;
          } else if constexpr (OBF) {
            union { __hip_bfloat16 h[4]; ull u; } P;
#pragma unroll
            for (int rg = 0; rg < 4; rg++) P.h[rg] = __float2bfloat16(v[rg]);
            *(ull*)(Cb + base * 2) = P.u;
          } else {
            *(float4*)(Cb + base * 4) = *(const float4*)v;
          }
        } else {
          const long long crow = n0 + wn + j * 16 + lm;
          const long long mb   = m0 + wm + i * 16 + kq * 4;
          if constexpr (EPI == 1) {
#pragma unroll
            for (int rg = 0; rg < 4; rg++) v[rg] = fmaxf(v[rg], 0.0f);
          }
          const long long base = bz * sC + crow * (long long)ldC + mb;
          if constexpr (OBF) {
            union { __hip_bfloat16 h[4]; ull u; } P;
#pragma unroll
            for (int rg = 0; rg < 4; rg++) P.h[rg] = __float2bfloat16(v[rg]);
            *(ull*)(Cb + base * 2) = P.u;
          } else {
            *(float4*)(Cb + base * 4) = *(const float4*)v;
          }
        }
      }
    }
  }
}

// ============================================================================
// adj row-sums -> dinv = 1/sqrt(rowsum).  One wave per row. 16384 rows total.
// ============================================================================
__global__ __launch_bounds__(256) void rowsum_dinv(const float* __restrict__ g,
                                                   float* __restrict__ dinv)
{
  const int wave = threadIdx.x >> 6, lane = threadIdx.x & 63;
  const long long row = (long long)blockIdx.x * 4 + wave;
  const float4* p = (const float4*)(g + row * 1024);
  float s = 0.0f;
#pragma unroll
  for (int k = 0; k < 4; k++) {
    float4 v = p[lane + k * 64];
    s += v.x + v.y + v.z + v.w;
  }
#pragma unroll
  for (int o = 32; o > 0; o >>= 1) s += __shfl_down(s, o);
  if (lane == 0) dinv[row] = 1.0f / sqrtf(s);
}

// ============================================================================
// adj_bf16[g][b][i][j] = graphs[b][g][i][j] * dinv[i] * dinv[j]  (graph-major)
// ============================================================================
__global__ __launch_bounds__(256) void scale_adj(const float* __restrict__ g,
                                                 const float* __restrict__ dinv,
                                                 __hip_bfloat16* __restrict__ out)
{
  const long long t = (long long)blockIdx.x * 256 + threadIdx.x;
  const long long e = t * 4;
  const int m = (int)(e >> 20);
  const int i = (int)((e >> 10) & 1023);
  const int j = (int)(e & 1023);
  const float4 v  = *(const float4*)(g + e);
  const float  di = dinv[m * 1024 + i];
  const float4 dj = *(const float4*)(dinv + m * 1024 + j);
  const int om = (m & 1) * 8 + (m >> 1);
  union { __hip_bfloat16 h[4]; ull u; } r;
  r.h[0] = __float2bfloat16(v.x * di * dj.x);
  r.h[1] = __float2bfloat16(v.y * di * dj.y);
  r.h[2] = __float2bfloat16(v.z * di * dj.z);
  r.h[3] = __float2bfloat16(v.w * di * dj.w);
  *(ull*)(out + ((long long)om << 20) + (long long)i * 1024 + j) = r.u;
}

// ============================================================================
// transpose + convert to bf16: out[C,R] = in[R,C], batched via grid.z
// ============================================================================
template<typename TIN>
__global__ void transpose_conv(const TIN* __restrict__ in, __hip_bfloat16* __restrict__ out,
                               int R, int C, long long sIn, long long sOut)
{
  __shared__ __hip_bfloat16 tile[32][33];
  in  += (long long)blockIdx.z * sIn;
  out += (long long)blockIdx.z * sOut;
  const int c0 = blockIdx.x * 32, r0 = blockIdx.y * 32;
  const int tx = threadIdx.x, ty = threadIdx.y;
#pragma unroll
  for (int i = 0; i < 32; i += 8)
    tile[ty + i][tx] = __float2bfloat16((float)in[(long long)(r0 + ty + i) * C + c0 + tx]);
  __syncthreads();
#pragma unroll
  for (int i = 0; i < 32; i += 8)
    out[(long long)(c0 + ty + i) * R + r0 + tx] = tile[tx][ty + i];
}

// ============================================================================
// residual + LayerNorm for BOTH graphs: rows [0,16384), g = row>>13.
// y = LN(nodes + V + col_b) -> bf16 slice of Gcat[r, g*768 : +768].  V bf16.
// ============================================================================
__global__ __launch_bounds__(256) void ln_residual2(
    const float* __restrict__ nodes, const __hip_bfloat16* __restrict__ V,
    const float* __restrict__ colb0, const float* __restrict__ colb1,
    const float* __restrict__ lng0,  const float* __restrict__ lng1,
    const float* __restrict__ lnb0,  const float* __restrict__ lnb1,
    __hip_bfloat16* __restrict__ gcat)
{
  const long long row = blockIdx.x;
  const int g = (int)(row >> 13);
  const long long rr = row & 8191;
  const float* __restrict__ colb = g ? colb1 : colb0;
  const float* __restrict__ lng  = g ? lng1  : lng0;
  const float* __restrict__ lnb  = g ? lnb1  : lnb0;
  const int t = threadIdx.x;
  const long long nbase = rr * 768;
  const long long vbase = row * 768;
  float x[3]; float s = 0.0f, ss = 0.0f;
#pragma unroll
  for (int i = 0; i < 3; i++) {
    const int c = t + i * 256;
    const float v = nodes[nbase + c] + __bfloat162float(V[vbase + c]) + colb[c];
    x[i] = v; s += v; ss += v * v;
  }
  __shared__ float red[8];
#pragma unroll
  for (int o = 32; o > 0; o >>= 1) { s += __shfl_down(s, o); ss += __shfl_down(ss, o); }
  const int wave = t >> 6, lane = t & 63;
  if (lane == 0) { red[wave] = s; red[4 + wave] = ss; }
  __syncthreads();
  if (t == 0) {
    red[0] = red[0] + red[1] + red[2] + red[3];
    red[4] = red[4] + red[5] + red[6] + red[7];
  }
  __syncthreads();
  const float mu  = red[0] * (1.0f / 768.0f);
  float var = red[4] * (1.0f / 768.0f) - mu * mu;
  var = fmaxf(var, 0.0f);
  const float rs = rsqrtf(var + 1e-12f);
#pragma unroll
  for (int i = 0; i < 3; i++) {
    const int c = t + i * 256;
    const float y = (x[i] - mu) * rs * lng[c] + lnb[c];
    gcat[rr * 1536 + g * 768 + c] = __float2bfloat16(y);
  }
}

// ============================================================================
// WeffT[n][k] (bf16, [768,1536]): folded gate weight
// ============================================================================
__global__ __launch_bounds__(256) void build_wefft(const float* __restrict__ gw,
                                                   __hip_bfloat16* __restrict__ wt)
{
  const int idx = blockIdx.x * 256 + threadIdx.x;
  const int n = idx / 1536, k = idx % 1536;
  float v;
  if (k < 768) v = gw[k * 768 + n] + gw[(1536 + k) * 768 + n] + gw[(2304 + k) * 768 + n];
  else {
    const int kk = k - 768;
    v = gw[(768 + kk) * 768 + n] + gw[(1536 + kk) * 768 + n] - gw[(2304 + kk) * 768 + n];
  }
  wt[idx] = __float2bfloat16(v);
}

// ============================================================================
extern "C" void kernel_launch(void* const* d_in, const int* in_sizes, int n_in,
                              void* d_out, int out_size, void* d_ws, size_t ws_size,
                              hipStream_t stream)
{
  const float* nodes  = (const float*)d_in[0];
  const float* graphs = (const float*)d_in[1];
  const float* gcn_w1[2] = { (const float*)d_in[2], (const float*)d_in[4] };
  const float* gcn_w2[2] = { (const float*)d_in[3], (const float*)d_in[5] };
  const float* exp_w[2]  = { (const float*)d_in[6],  (const float*)d_in[10] };
  const float* exp_b[2]  = { (const float*)d_in[7],  (const float*)d_in[11] };
  const float* col_w[2]  = { (const float*)d_in[8],  (const float*)d_in[12] };
  const float* col_b[2]  = { (const float*)d_in[9],  (const float*)d_in[13] };
  const float* gate_w = (const float*)d_in[14];
  const float* gate_b = (const float*)d_in[15];
  const float* ln_g[2] = { (const float*)d_in[16], (const float*)d_in[18] };
  const float* ln_b[2] = { (const float*)d_in[17], (const float*)d_in[19] };
  float* out = (float*)d_out;

  // ---- workspace carve-up (lifetime-aliased regions, unchanged) ----
  char* w = (char*)d_ws;
  auto alloc = [&](size_t bytes) { char* p = w; w += (bytes + 255) & ~(size_t)255; return p; };
  float*          dinv   = (float*)alloc(16384ULL * 4);
  char*           regA   = alloc(16ULL * 1024 * 1024 * 2);
  __hip_bfloat16* adj2   = (__hip_bfloat16*)regA;
  __hip_bfloat16* Gcat   = (__hip_bfloat16*)regA;
  __hip_bfloat16* wefft  = (__hip_bfloat16*)alloc(768ULL * 1536 * 2);
  __hip_bfloat16* bufA2  = (__hip_bfloat16*)alloc(16ULL * 1024 * 768 * 2);
  char*           regD   = alloc(16ULL * 1024 * 768 * 2);
  __hip_bfloat16* Xt     = (__hip_bfloat16*)regD;
  __hip_bfloat16* bufB2  = (__hip_bfloat16*)regD;
  __hip_bfloat16* X12    = (__hip_bfloat16*)alloc(2ULL * 8192 * 3072 * 2);
  __hip_bfloat16* wgt1   = (__hip_bfloat16*)alloc(2ULL * 3072 * 768 * 2);
  __hip_bfloat16* wgt2   = (__hip_bfloat16*)alloc(2ULL * 768 * 3072 * 2);

  const long long sW1 = 3072LL * 768;
  const long long sW2 = 768LL * 3072;
  const long long sNM = 1024LL * 768;
  const long long sBig = 8192LL * 3072;

  // ---- prep ----
  rowsum_dinv<<<4096, 256, 0, stream>>>(graphs, dinv);
  transpose_conv<float><<<dim3(24, 32, 8), dim3(32, 8), 0, stream>>>(
      nodes, Xt, 1024, 768, 1024LL * 768, 768LL * 1024);
  build_wefft<<<4608, 256, 0, stream>>>(gate_w, wefft);
  scale_adj<<<16384, 256, 0, stream>>>(graphs, dinv, adj2);
  for (int g = 0; g < 2; g++) {
    transpose_conv<float><<<dim3(96, 24, 1), dim3(32, 8), 0, stream>>>(
        gcn_w1[g], wgt1 + g * sW1, 768, 3072, 0, 0);
    transpose_conv<float><<<dim3(24, 96, 1), dim3(32, 8), 0, stream>>>(
        gcn_w2[g], wgt2 + g * sW2, 3072, 768, 0, 0);
  }

  // ---- batched pipeline on the template-cadence GEMM ----
  // AX = adj @ X   [1024,1024]@[1024,768] x16  -> bufA2
  gemm256<0><<<dim3(4, 3, 16), 512, 0, stream>>>(
      adj2, 1LL << 20, Xt, 0, sNM, 1024, bufA2, sNM, 768,
      nullptr, nullptr, 1024);
  // X1 = relu(AX @ W1)   [8192,768]@[768,3072] x2 -> X12
  gemm256<1><<<dim3(32, 12, 2), 512, 0, stream>>>(
      bufA2, 8192LL * 768, wgt1, 0, sW1, 768, X12, sBig, 3072,
      nullptr, nullptr, 768);
  // T2^T = w2T @ X1^T (swapped operands: A=w2T[768,3072], Bt=X1[8192,3072])
  //   -> bufA2 as [2][768][8192]
  gemm256<0><<<dim3(3, 32, 2), 512, 0, stream>>>(
      wgt2, sW2, X12, 0, sBig, 3072, bufA2, 768LL * 8192, 8192,
      nullptr, nullptr, 3072);
  // rebuild weight regions with exp/col transposes (w1T/w2T dead)
  for (int g = 0; g < 2; g++) {
    transpose_conv<float><<<dim3(96, 24, 1), dim3(32, 8), 0, stream>>>(
        exp_w[g], wgt1 + g * sW1, 768, 3072, 0, 0);
    transpose_conv<float><<<dim3(24, 96, 1), dim3(32, 8), 0, stream>>>(
        col_w[g], wgt2 + g * sW2, 3072, 768, 0, 0);
  }
  // G = relu(adj @ T2)   [1024,1024]@[1024,768] x16 -> bufB2 (Xt dead)
  gemm256<1><<<dim3(4, 3, 16), 512, 0, stream>>>(
      adj2, 1LL << 20, bufA2, 768LL * 8192, 1024, 8192, bufB2, sNM, 768,
      nullptr, nullptr, 1024);
  // U = gelu(G @ expW + b)   [8192,768]@[768,3072] x2 -> X12 (X1 dead)
  gemm256<2><<<dim3(32, 12, 2), 512, 0, stream>>>(
      bufB2, 8192LL * 768, wgt1, 0, sW1, 768, X12, sBig, 3072,
      exp_b[0], exp_b[1], 768);
  // V = U @ colW   [8192,3072]@[3072,768] x2 -> bufA2 (T2^T dead)
  gemm256<0><<<dim3(32, 3, 2), 512, 0, stream>>>(
      X12, sBig, wgt2, 0, sW2, 3072, bufA2, 8192LL * 768, 768,
      nullptr, nullptr, 3072);
  // LN(nodes + V + col_b) both graphs -> Gcat (adj2 dead)
  ln_residual2<<<16384, 256, 0, stream>>>(
      nodes, bufA2, col_b[0], col_b[1], ln_g[0], ln_g[1], ln_b[0], ln_b[1], Gcat);
  // out = sigmoid(Gcat @ WeffT^T + gate_b) blend -> fused gate epilogue
  gemm_bt<3, 0, 0, 1><<<dim3(64, 6, 1), 256, 0, stream>>>(
      Gcat, 0, wefft, 0, 0, 1536, out, 0, 768,
      gate_b, nullptr, Gcat, 1536);
}

// Round 8
// 798.302 us; speedup vs baseline: 1.0445x; 1.0445x over previous
//
#include <hip/hip_runtime.h>
#include <hip/hip_bf16.h>

typedef __bf16 b8v __attribute__((ext_vector_type(8)));
typedef float  f4v __attribute__((ext_vector_type(4)));
typedef unsigned long long ull;

#define AS3(p)  ((__attribute__((address_space(3))) void*)(p))
#define AS1C(p) ((const __attribute__((address_space(1))) void*)(p))
#define MFMA16(a, b, c) __builtin_amdgcn_mfma_f32_16x16x32_bf16((a), (b), (c), 0, 0, 0)

// ============================================================================
// gemm256: C[M,N] = A[M,K] @ Bt[N,K]^T  (bf16 in/out, fp32 acc)
// R6 kernel (best measured: 803.8 us total) + SWZ template param.
// 256x256 tile, BK=64, 512 thr = 8 waves (2Mx4N), per-wave 128x64.
// LDS [dbuf2][half2][128x64] x {A,B} = 128 KiB.  4 phases per K-tile
// (C-quadrants): {ds_read 12/4/8/0 -> stage 1 half-tile -> barrier ->
// lgkmcnt(0)+sched_barrier -> setprio(1) -> 16 MFMA -> setprio(0) -> barrier}.
// Staggered staging: tile t: phA Ah1(t+1), phB Bh0(t+1), phC Bh1(t+1),
// phD Ah0(t+2); boundary vmcnt(2) at phD (never 0 in steady state).
// Swizzle: chunk c of row r holds global chunk c^(r&7) via pre-swizzled
// global source (linear LDS dest); reads apply same XOR. 0 bank conflicts
// (R6 rocprof).
// SWZ=1 [T1]: 1D launch of 192 blocks, logical grid (4,3,16); chunked XCD
// remap: logical = (hw&7)*24 + hw>>3 -> each XCD owns 2 complete z-slices
// (adj 2MB + Xt 1.5MB per slice ~ fits 4MB XCD L2).  Targets the measured
// 4.1x L2-miss over-read on the adjacency GEMMs (R7: FETCH 186MB vs 45MB).
// EPI: 0 none, 1 relu, 2 bias+gelu (bias by bz&1).  Output bf16.
// Bt batch offset = (z>>3)*sBg + (z&7)*sBb.
// ============================================================================
template<int EPI, int SWZ>
__global__ __launch_bounds__(512, 2) void gemm256(
    const __hip_bfloat16* __restrict__ A,  long long sA,
    const __hip_bfloat16* __restrict__ Bt, long long sBg, long long sBb, int ldB,
    __hip_bfloat16* __restrict__ C, long long sC, int ldC,
    const float* __restrict__ bias0, const float* __restrict__ bias1, int K)
{
  int bx, by, bz;
  if constexpr (SWZ) {
    // 1D launch, nwg = 192 (divisible by 8 -> bijective chunk remap).
    const int logical = ((int)blockIdx.x & 7) * 24 + ((int)blockIdx.x >> 3);
    bz = logical / 12;
    const int r = logical - bz * 12;
    by = r >> 2; bx = r & 3;
  } else {
    bx = blockIdx.x; by = blockIdx.y; bz = blockIdx.z;
  }
  A  += (long long)bz * sA;
  Bt += (long long)(bz >> 3) * sBg + (long long)(bz & 7) * sBb;
  const float* __restrict__ bias = (bz & 1) ? bias1 : bias0;

  __shared__ __hip_bfloat16 As[2][2][8192];   // [dbuf][half][128 rows x 64 k]
  __shared__ __hip_bfloat16 Bs[2][2][8192];

  const int tid  = threadIdx.x;
  const int lane = tid & 63;
  const int wave = tid >> 6;
  const int wr = wave >> 2;          // 0..1 : M half (128 rows)
  const int wc = wave & 3;           // 0..3 : N quarter (64 cols)
  const int lm = lane & 15;
  const int kq = lane >> 4;

  const long long m0 = (long long)bx * 256;
  const long long n0 = (long long)by * 256;

  // staging: thread -> (row sr, chunk sc); global chunk pre-swizzled sc^(sr&7)
  const int sr  = tid >> 3;                    // 0..63
  const int sc  = tid & 7;
  const int gch = sc ^ (sr & 7);
  const int ldsE = tid * 8;                    // element offset of 16B slot

  auto stageA = [&](int d, int h, int kt) {
    const __hip_bfloat16* s0 = A + (m0 + h * 128 + sr) * (long long)K + (long long)kt * 64 + gch * 8;
    __builtin_amdgcn_global_load_lds(AS1C(s0),            AS3(&As[d][h][ldsE]),        16, 0, 0);
    __builtin_amdgcn_global_load_lds(AS1C(s0 + 64LL * K), AS3(&As[d][h][4096 + ldsE]), 16, 0, 0);
  };
  auto stageB = [&](int d, int h, int kt) {
    const __hip_bfloat16* s0 = Bt + (n0 + h * 128 + sr) * (long long)ldB + (long long)kt * 64 + gch * 8;
    __builtin_amdgcn_global_load_lds(AS1C(s0),              AS3(&Bs[d][h][ldsE]),        16, 0, 0);
    __builtin_amdgcn_global_load_lds(AS1C(s0 + 64LL * ldB), AS3(&Bs[d][h][4096 + ldsE]), 16, 0, 0);
  };

  const int NT = K >> 6;
  // prologue: tile0 fully + Ah0(tile1); wait tile0 (8 loads) -> vmcnt(2)
  stageA(0, 0, 0); stageA(0, 1, 0); stageB(0, 0, 0); stageB(0, 1, 0);
  stageA(1, 0, 1);
  asm volatile("s_waitcnt vmcnt(2)" ::: "memory");
  __builtin_amdgcn_s_barrier();

  f4v acc[8][4];
  const f4v fz = {0.0f, 0.0f, 0.0f, 0.0f};
#pragma unroll
  for (int i = 0; i < 8; i++)
#pragma unroll
    for (int j = 0; j < 4; j++) acc[i][j] = fz;

  // lane read constants: elem off = frag*1024 + lm*64 + ((kh*4+kq)^(lm&7))*8
  const int rb  = lm * 64;
  const int cs0 = ((kq)     ^ (lm & 7)) * 8;   // kh=0
  const int cs1 = ((4 + kq) ^ (lm & 7)) * 8;   // kh=1

  for (int kt = 0; kt < NT; ++kt) {
    const int d = kt & 1, dn = d ^ 1;
    const __hip_bfloat16* Ab = &As[d][wr][0];
    const __hip_bfloat16* Bb = &Bs[d][wc >> 1][(wc & 1) * 4096];
    const bool st1 = (kt + 1 < NT);
    b8v afL[8], afH[8], bfL[4], bfH[4];

    // ---- phase A: quadrant (fi0-3, fj0-1); reads 12; stage Ah1(t+1) ----
#pragma unroll
    for (int f = 0; f < 4; f++) {
      afL[f * 2]     = *(const b8v*)(Ab + f * 1024 + rb + cs0);
      afL[f * 2 + 1] = *(const b8v*)(Ab + f * 1024 + rb + cs1);
    }
#pragma unroll
    for (int f = 0; f < 2; f++) {
      bfL[f * 2]     = *(const b8v*)(Bb + f * 1024 + rb + cs0);
      bfL[f * 2 + 1] = *(const b8v*)(Bb + f * 1024 + rb + cs1);
    }
    if (st1) stageA(dn, 1, kt + 1);
    __builtin_amdgcn_s_barrier();
    asm volatile("s_waitcnt lgkmcnt(0)" ::: "memory");
    __builtin_amdgcn_sched_barrier(0);
    __builtin_amdgcn_s_setprio(1);
#pragma unroll
    for (int i = 0; i < 4; i++)
#pragma unroll
      for (int j = 0; j < 2; j++) acc[i][j] = MFMA16(bfL[j * 2], afL[i * 2], acc[i][j]);
#pragma unroll
    for (int i = 0; i < 4; i++)
#pragma unroll
      for (int j = 0; j < 2; j++) acc[i][j] = MFMA16(bfL[j * 2 + 1], afL[i * 2 + 1], acc[i][j]);
    __builtin_amdgcn_s_setprio(0);
    __builtin_amdgcn_s_barrier();

    // ---- phase B: quadrant (fi0-3, fj2-3); reads 4; stage Bh0(t+1) ----
#pragma unroll
    for (int f = 0; f < 2; f++) {
      bfH[f * 2]     = *(const b8v*)(Bb + (2 + f) * 1024 + rb + cs0);
      bfH[f * 2 + 1] = *(const b8v*)(Bb + (2 + f) * 1024 + rb + cs1);
    }
    if (st1) stageB(dn, 0, kt + 1);
    __builtin_amdgcn_s_barrier();
    asm volatile("s_waitcnt lgkmcnt(0)" ::: "memory");
    __builtin_amdgcn_sched_barrier(0);
    __builtin_amdgcn_s_setprio(1);
#pragma unroll
    for (int i = 0; i < 4; i++)
#pragma unroll
      for (int j = 0; j < 2; j++) acc[i][2 + j] = MFMA16(bfH[j * 2], afL[i * 2], acc[i][2 + j]);
#pragma unroll
    for (int i = 0; i < 4; i++)
#pragma unroll
      for (int j = 0; j < 2; j++) acc[i][2 + j] = MFMA16(bfH[j * 2 + 1], afL[i * 2 + 1], acc[i][2 + j]);
    __builtin_amdgcn_s_setprio(0);
    __builtin_amdgcn_s_barrier();

    // ---- phase C: quadrant (fi4-7, fj0-1); reads 8; stage Bh1(t+1) ----
#pragma unroll
    for (int f = 0; f < 4; f++) {
      afH[f * 2]     = *(const b8v*)(Ab + (4 + f) * 1024 + rb + cs0);
      afH[f * 2 + 1] = *(const b8v*)(Ab + (4 + f) * 1024 + rb + cs1);
    }
    if (st1) stageB(dn, 1, kt + 1);
    __builtin_amdgcn_s_barrier();
    asm volatile("s_waitcnt lgkmcnt(0)" ::: "memory");
    __builtin_amdgcn_sched_barrier(0);
    __builtin_amdgcn_s_setprio(1);
#pragma unroll
    for (int i = 0; i < 4; i++)
#pragma unroll
      for (int j = 0; j < 2; j++) acc[4 + i][j] = MFMA16(bfL[j * 2], afH[i * 2], acc[4 + i][j]);
#pragma unroll
    for (int i = 0; i < 4; i++)
#pragma unroll
      for (int j = 0; j < 2; j++) acc[4 + i][j] = MFMA16(bfL[j * 2 + 1], afH[i * 2 + 1], acc[4 + i][j]);
    __builtin_amdgcn_s_setprio(0);
    __builtin_amdgcn_s_barrier();

    // ---- phase D: quadrant (fi4-7, fj2-3); reads 0; stage Ah0(t+2);
    //      boundary vmcnt(2) (t+1 resident, only Ah0(t+2) outstanding) ----
    if (kt + 2 < NT) stageA(d, 0, kt + 2);
    __builtin_amdgcn_s_setprio(1);
#pragma unroll
    for (int i = 0; i < 4; i++)
#pragma unroll
      for (int j = 0; j < 2; j++) acc[4 + i][2 + j] = MFMA16(bfH[j * 2], afH[i * 2], acc[4 + i][2 + j]);
#pragma unroll
    for (int i = 0; i < 4; i++)
#pragma unroll
      for (int j = 0; j < 2; j++) acc[4 + i][2 + j] = MFMA16(bfH[j * 2 + 1], afH[i * 2 + 1], acc[4 + i][2 + j]);
    __builtin_amdgcn_s_setprio(0);
    if (kt + 2 < NT) asm volatile("s_waitcnt vmcnt(2)" ::: "memory");
    else             asm volatile("s_waitcnt vmcnt(0)" ::: "memory");
    __builtin_amdgcn_s_barrier();
  }

  // ---- epilogue: lane holds rows m0+wr*128+i*16+lm, cols n0+wc*64+j*16+kq*4 ----
#pragma unroll
  for (int i = 0; i < 8; i++) {
    const long long row = m0 + wr * 128 + i * 16 + lm;
#pragma unroll
    for (int j = 0; j < 4; j++) {
      const int colb = (int)n0 + wc * 64 + j * 16 + kq * 4;
      float v[4];
#pragma unroll
      for (int rg = 0; rg < 4; rg++) v[rg] = acc[i][j][rg];
      if constexpr (EPI == 1) {
#pragma unroll
        for (int rg = 0; rg < 4; rg++) v[rg] = fmaxf(v[rg], 0.0f);
      }
      if constexpr (EPI == 2) {
        const float4 b4 = *(const float4*)(bias + colb);
        const float* bb = (const float*)&b4;
#pragma unroll
        for (int rg = 0; rg < 4; rg++) {
          float x = v[rg] + bb[rg];
          v[rg] = 0.5f * x * (1.0f + erff(x * 0.70710678118654752f));
        }
      }
      union { __hip_bfloat16 h[4]; ull u; } P;
#pragma unroll
      for (int rg = 0; rg < 4; rg++) P.h[rg] = __float2bfloat16(v[rg]);
      *(ull*)(C + (long long)bz * sC + row * (long long)ldC + colb) = P.u;
    }
  }
}

// ============================================================================
// OLD 128x128 GEMM — retained for the gate GEMM (EPI=3).  Verified baseline.
// ============================================================================
template<int EPI, int OBF, int ORIENT, int MP>
__global__ __launch_bounds__(256) void gemm_bt(
    const __hip_bfloat16* __restrict__ A,  long long sA,
    const __hip_bfloat16* __restrict__ Bt, long long sBg, long long sBb, int ldB,
    void* __restrict__ Cv, long long sC, int ldC,
    const float* __restrict__ bias0, const float* __restrict__ bias1,
    const __hip_bfloat16* __restrict__ gcat, int K)
{
  const int bz = blockIdx.z;
  A  += (long long)bz * sA;
  Bt += (long long)(bz >> 3) * sBg + (long long)(bz & 7) * sBb;
  const float* __restrict__ bias = (bz & 1) ? bias1 : bias0;

  __shared__ __hip_bfloat16 As[128 * 32];
  __shared__ __hip_bfloat16 Bs[128 * 32];

  const int tid  = threadIdx.x;
  const int lane = tid & 63;
  const int wave = tid >> 6;

  const long long mBase = (long long)blockIdx.x * (MP * 128);
  const long long n0    = (long long)blockIdx.y * 128;

  const int r  = tid >> 2;
  const int kc = (tid & 3) ^ ((r >> 2) & 3);
  const __hip_bfloat16* aRow = A  + (mBase + r) * (long long)K   + kc * 8;
  const __hip_bfloat16* bRow = Bt + (n0 + r)    * (long long)ldB + kc * 8;

  const int wm = (wave & 1) * 64;
  const int wn = (wave >> 1) * 64;
  const int lm = lane & 15;
  const int kq = lane >> 4;

  const int sw   = (lm >> 2) & 3;
  const int aOff = (wm + lm) * 32 + (kq ^ sw) * 8;
  const int bOff = (wn + lm) * 32 + (kq ^ sw) * 8;

  auto stage = [&](long long aoff, int k0) {
    const __hip_bfloat16* a = aRow + aoff + k0;
    const __hip_bfloat16* b = bRow + k0;
    __builtin_amdgcn_global_load_lds(AS1C(a),              AS3(As + tid * 8),        16, 0, 0);
    __builtin_amdgcn_global_load_lds(AS1C(a + 64LL * K),   AS3(As + 2048 + tid * 8), 16, 0, 0);
    __builtin_amdgcn_global_load_lds(AS1C(b),              AS3(Bs + tid * 8),        16, 0, 0);
    __builtin_amdgcn_global_load_lds(AS1C(b + 64LL * ldB), AS3(Bs + 2048 + tid * 8), 16, 0, 0);
  };

  stage(0, 0);

  const f4v fzero = {0.0f, 0.0f, 0.0f, 0.0f};
  char* Cb = (char*)Cv;

  for (int p = 0; p < MP; ++p) {
    const long long aoff = (long long)p * 128 * K;

    f4v acc[4][4];
#pragma unroll
    for (int i = 0; i < 4; i++)
#pragma unroll
      for (int j = 0; j < 4; j++) acc[i][j] = fzero;

    for (int k0 = 0; k0 < K; k0 += 32) {
      __syncthreads();

      b8v af[4], bf[4];
#pragma unroll
      for (int i = 0; i < 4; i++) af[i] = *(const b8v*)(As + aOff + i * 16 * 32);
#pragma unroll
      for (int j = 0; j < 4; j++) bf[j] = *(const b8v*)(Bs + bOff + j * 16 * 32);

      __syncthreads();

      if (k0 + 32 < K)            stage(aoff, k0 + 32);
      else if (MP > 1 && p + 1 < MP) stage(aoff + 128LL * K, 0);

#pragma unroll
      for (int i = 0; i < 4; i++)
#pragma unroll
        for (int j = 0; j < 4; j++) {
          if constexpr (ORIENT == 0)
            acc[i][j] = __builtin_amdgcn_mfma_f32_16x16x32_bf16(bf[j], af[i], acc[i][j], 0, 0, 0);
          else
            acc[i][j] = __builtin_amdgcn_mfma_f32_16x16x32_bf16(af[i], bf[j], acc[i][j], 0, 0, 0);
        }
    }

    const long long m0 = mBase + (long long)p * 128;
#pragma unroll
    for (int i = 0; i < 4; i++) {
#pragma unroll
      for (int j = 0; j < 4; j++) {
        float v[4];
#pragma unroll
        for (int rg = 0; rg < 4; rg++) v[rg] = acc[i][j][rg];

        if constexpr (ORIENT == 0) {
          const long long row  = m0 + wm + i * 16 + lm;
          const int       colb = (int)n0 + wn + j * 16 + kq * 4;
          if constexpr (EPI == 1) {
#pragma unroll
            for (int rg = 0; rg < 4; rg++) v[rg] = fmaxf(v[rg], 0.0f);
          }
          if constexpr (EPI == 2) {
            const float4 b4 = *(const float4*)(bias + colb);
            const float* bb = (const float*)&b4;
#pragma unroll
            for (int rg = 0; rg < 4; rg++) {
              float x = v[rg] + bb[rg];
              v[rg] = 0.5f * x * (1.0f + erff(x * 0.70710678118654752f));
            }
          }
          const long long base = bz * sC + row * (long long)ldC + colb;
          if constexpr (EPI == 3) {
            const float4 b4 = *(const float4*)(bias0 + colb);
            const float* bb = (const float*)&b4;
            union { __hip_bfloat16 h[4]; ull u; } g1, g2;
            g1.u = *(const ull*)(gcat + row * 1536 + colb);
            g2.u = *(const ull*)(gcat + row * 1536 + 768 + colb);
            float o[4];
#pragma unroll
            for (int rg = 0; rg < 4; rg++) {
              const float s = 1.0f / (1.0f + expf(-(v[rg] + bb[rg])));
              o[rg] = s * __bfloat162float(g1.h[rg]) +
                      (1.0f - s) * __bfloat162float(g2.h[rg]);
            }
            *(float4*)(Cb + base * 4) = *(const float4*)o;
          } else if constexpr (OBF) {
            union { __hip_bfloat16 h[4]; ull u; } P;
#pragma unroll
            for (int rg = 0; rg < 4; rg++) P.h[rg] = __float2bfloat16(v[rg]);
            *(ull*)(Cb + base * 2) = P.u;
          } else {
            *(float4*)(Cb + base * 4) = *(const float4*)v;
          }
        } else {
          const long long crow = n0 + wn + j * 16 + lm;
          const long long mb   = m0 + wm + i * 16 + kq * 4;
          if constexpr (EPI == 1) {
#pragma unroll
            for (int rg = 0; rg < 4; rg++) v[rg] = fmaxf(v[rg], 0.0f);
          }
          const long long base = bz * sC + crow * (long long)ldC + mb;
          if constexpr (OBF) {
            union { __hip_bfloat16 h[4]; ull u; } P;
#pragma unroll
            for (int rg = 0; rg < 4; rg++) P.h[rg] = __float2bfloat16(v[rg]);
            *(ull*)(Cb + base * 2) = P.u;
          } else {
            *(float4*)(Cb + base * 4) = *(const float4*)v;
          }
        }
      }
    }
  }
}

// ============================================================================
// adj row-sums -> dinv = 1/sqrt(rowsum).  One wave per row. 16384 rows total.
// ============================================================================
__global__ __launch_bounds__(256) void rowsum_dinv(const float* __restrict__ g,
                                                   float* __restrict__ dinv)
{
  const int wave = threadIdx.x >> 6, lane = threadIdx.x & 63;
  const long long row = (long long)blockIdx.x * 4 + wave;
  const float4* p = (const float4*)(g + row * 1024);
  float s = 0.0f;
#pragma unroll
  for (int k = 0; k < 4; k++) {
    float4 v = p[lane + k * 64];
    s += v.x + v.y + v.z + v.w;
  }
#pragma unroll
  for (int o = 32; o > 0; o >>= 1) s += __shfl_down(s, o);
  if (lane == 0) dinv[row] = 1.0f / sqrtf(s);
}

// ============================================================================
// adj_bf16[g][b][i][j] = graphs[b][g][i][j] * dinv[i] * dinv[j]  (graph-major)
// ============================================================================
__global__ __launch_bounds__(256) void scale_adj(const float* __restrict__ g,
                                                 const float* __restrict__ dinv,
                                                 __hip_bfloat16* __restrict__ out)
{
  const long long t = (long long)blockIdx.x * 256 + threadIdx.x;
  const long long e = t * 4;
  const int m = (int)(e >> 20);
  const int i = (int)((e >> 10) & 1023);
  const int j = (int)(e & 1023);
  const float4 v  = *(const float4*)(g + e);
  const float  di = dinv[m * 1024 + i];
  const float4 dj = *(const float4*)(dinv + m * 1024 + j);
  const int om = (m & 1) * 8 + (m >> 1);
  union { __hip_bfloat16 h[4]; ull u; } r;
  r.h[0] = __float2bfloat16(v.x * di * dj.x);
  r.h[1] = __float2bfloat16(v.y * di * dj.y);
  r.h[2] = __float2bfloat16(v.z * di * dj.z);
  r.h[3] = __float2bfloat16(v.w * di * dj.w);
  *(ull*)(out + ((long long)om << 20) + (long long)i * 1024 + j) = r.u;
}

// ============================================================================
// transpose + convert to bf16: out[C,R] = in[R,C], batched via grid.z
// ============================================================================
template<typename TIN>
__global__ void transpose_conv(const TIN* __restrict__ in, __hip_bfloat16* __restrict__ out,
                               int R, int C, long long sIn, long long sOut)
{
  __shared__ __hip_bfloat16 tile[32][33];
  in  += (long long)blockIdx.z * sIn;
  out += (long long)blockIdx.z * sOut;
  const int c0 = blockIdx.x * 32, r0 = blockIdx.y * 32;
  const int tx = threadIdx.x, ty = threadIdx.y;
#pragma unroll
  for (int i = 0; i < 32; i += 8)
    tile[ty + i][tx] = __float2bfloat16((float)in[(long long)(r0 + ty + i) * C + c0 + tx]);
  __syncthreads();
#pragma unroll
  for (int i = 0; i < 32; i += 8)
    out[(long long)(c0 + ty + i) * R + r0 + tx] = tile[tx][ty + i];
}

// ============================================================================
// residual + LayerNorm for BOTH graphs: rows [0,16384), g = row>>13.
// y = LN(nodes + V + col_b) -> bf16 slice of Gcat[r, g*768 : +768].  V bf16.
// ============================================================================
__global__ __launch_bounds__(256) void ln_residual2(
    const float* __restrict__ nodes, const __hip_bfloat16* __restrict__ V,
    const float* __restrict__ colb0, const float* __restrict__ colb1,
    const float* __restrict__ lng0,  const float* __restrict__ lng1,
    const float* __restrict__ lnb0,  const float* __restrict__ lnb1,
    __hip_bfloat16* __restrict__ gcat)
{
  const long long row = blockIdx.x;
  const int g = (int)(row >> 13);
  const long long rr = row & 8191;
  const float* __restrict__ colb = g ? colb1 : colb0;
  const float* __restrict__ lng  = g ? lng1  : lng0;
  const float* __restrict__ lnb  = g ? lnb1  : lnb0;
  const int t = threadIdx.x;
  const long long nbase = rr * 768;
  const long long vbase = row * 768;
  float x[3]; float s = 0.0f, ss = 0.0f;
#pragma unroll
  for (int i = 0; i < 3; i++) {
    const int c = t + i * 256;
    const float v = nodes[nbase + c] + __bfloat162float(V[vbase + c]) + colb[c];
    x[i] = v; s += v; ss += v * v;
  }
  __shared__ float red[8];
#pragma unroll
  for (int o = 32; o > 0; o >>= 1) { s += __shfl_down(s, o); ss += __shfl_down(ss, o); }
  const int wave = t >> 6, lane = t & 63;
  if (lane == 0) { red[wave] = s; red[4 + wave] = ss; }
  __syncthreads();
  if (t == 0) {
    red[0] = red[0] + red[1] + red[2] + red[3];
    red[4] = red[4] + red[5] + red[6] + red[7];
  }
  __syncthreads();
  const float mu  = red[0] * (1.0f / 768.0f);
  float var = red[4] * (1.0f / 768.0f) - mu * mu;
  var = fmaxf(var, 0.0f);
  const float rs = rsqrtf(var + 1e-12f);
#pragma unroll
  for (int i = 0; i < 3; i++) {
    const int c = t + i * 256;
    const float y = (x[i] - mu) * rs * lng[c] + lnb[c];
    gcat[rr * 1536 + g * 768 + c] = __float2bfloat16(y);
  }
}

// ============================================================================
// WeffT[n][k] (bf16, [768,1536]): folded gate weight
// ============================================================================
__global__ __launch_bounds__(256) void build_wefft(const float* __restrict__ gw,
                                                   __hip_bfloat16* __restrict__ wt)
{
  const int idx = blockIdx.x * 256 + threadIdx.x;
  const int n = idx / 1536, k = idx % 1536;
  float v;
  if (k < 768) v = gw[k * 768 + n] + gw[(1536 + k) * 768 + n] + gw[(2304 + k) * 768 + n];
  else {
    const int kk = k - 768;
    v = gw[(768 + kk) * 768 + n] + gw[(1536 + kk) * 768 + n] - gw[(2304 + kk) * 768 + n];
  }
  wt[idx] = __float2bfloat16(v);
}

// ============================================================================
extern "C" void kernel_launch(void* const* d_in, const int* in_sizes, int n_in,
                              void* d_out, int out_size, void* d_ws, size_t ws_size,
                              hipStream_t stream)
{
  const float* nodes  = (const float*)d_in[0];
  const float* graphs = (const float*)d_in[1];
  const float* gcn_w1[2] = { (const float*)d_in[2], (const float*)d_in[4] };
  const float* gcn_w2[2] = { (const float*)d_in[3], (const float*)d_in[5] };
  const float* exp_w[2]  = { (const float*)d_in[6],  (const float*)d_in[10] };
  const float* exp_b[2]  = { (const float*)d_in[7],  (const float*)d_in[11] };
  const float* col_w[2]  = { (const float*)d_in[8],  (const float*)d_in[12] };
  const float* col_b[2]  = { (const float*)d_in[9],  (const float*)d_in[13] };
  const float* gate_w = (const float*)d_in[14];
  const float* gate_b = (const float*)d_in[15];
  const float* ln_g[2] = { (const float*)d_in[16], (const float*)d_in[18] };
  const float* ln_b[2] = { (const float*)d_in[17], (const float*)d_in[19] };
  float* out = (float*)d_out;

  // ---- workspace carve-up (lifetime-aliased regions, unchanged) ----
  char* w = (char*)d_ws;
  auto alloc = [&](size_t bytes) { char* p = w; w += (bytes + 255) & ~(size_t)255; return p; };
  float*          dinv   = (float*)alloc(16384ULL * 4);
  char*           regA   = alloc(16ULL * 1024 * 1024 * 2);
  __hip_bfloat16* adj2   = (__hip_bfloat16*)regA;
  __hip_bfloat16* Gcat   = (__hip_bfloat16*)regA;
  __hip_bfloat16* wefft  = (__hip_bfloat16*)alloc(768ULL * 1536 * 2);
  __hip_bfloat16* bufA2  = (__hip_bfloat16*)alloc(16ULL * 1024 * 768 * 2);
  char*           regD   = alloc(16ULL * 1024 * 768 * 2);
  __hip_bfloat16* Xt     = (__hip_bfloat16*)regD;
  __hip_bfloat16* bufB2  = (__hip_bfloat16*)regD;
  __hip_bfloat16* X12    = (__hip_bfloat16*)alloc(2ULL * 8192 * 3072 * 2);
  __hip_bfloat16* wgt1   = (__hip_bfloat16*)alloc(2ULL * 3072 * 768 * 2);
  __hip_bfloat16* wgt2   = (__hip_bfloat16*)alloc(2ULL * 768 * 3072 * 2);

  const long long sW1 = 3072LL * 768;
  const long long sW2 = 768LL * 3072;
  const long long sNM = 1024LL * 768;
  const long long sBig = 8192LL * 3072;

  // ---- prep ----
  rowsum_dinv<<<4096, 256, 0, stream>>>(graphs, dinv);
  transpose_conv<float><<<dim3(24, 32, 8), dim3(32, 8), 0, stream>>>(
      nodes, Xt, 1024, 768, 1024LL * 768, 768LL * 1024);
  build_wefft<<<4608, 256, 0, stream>>>(gate_w, wefft);
  scale_adj<<<16384, 256, 0, stream>>>(graphs, dinv, adj2);
  for (int g = 0; g < 2; g++) {
    transpose_conv<float><<<dim3(96, 24, 1), dim3(32, 8), 0, stream>>>(
        gcn_w1[g], wgt1 + g * sW1, 768, 3072, 0, 0);
    transpose_conv<float><<<dim3(24, 96, 1), dim3(32, 8), 0, stream>>>(
        gcn_w2[g], wgt2 + g * sW2, 3072, 768, 0, 0);
  }

  // ---- batched pipeline (R6 GEMM; adj GEMMs get T1 XCD-chunked launch) ----
  // AX = adj @ X   [1024,1024]@[1024,768] x16  -> bufA2   [SWZ=1: 1D 192]
  gemm256<0, 1><<<192, 512, 0, stream>>>(
      adj2, 1LL << 20, Xt, 0, sNM, 1024, bufA2, sNM, 768,
      nullptr, nullptr, 1024);
  // X1 = relu(AX @ W1)   [8192,768]@[768,3072] x2 -> X12
  gemm256<1, 0><<<dim3(32, 12, 2), 512, 0, stream>>>(
      bufA2, 8192LL * 768, wgt1, 0, sW1, 768, X12, sBig, 3072,
      nullptr, nullptr, 768);
  // T2^T = w2T @ X1^T (swapped operands: A=w2T[768,3072], Bt=X1[8192,3072])
  //   -> bufA2 as [2][768][8192]
  gemm256<0, 0><<<dim3(3, 32, 2), 512, 0, stream>>>(
      wgt2, sW2, X12, 0, sBig, 3072, bufA2, 768LL * 8192, 8192,
      nullptr, nullptr, 3072);
  // rebuild weight regions with exp/col transposes (w1T/w2T dead)
  for (int g = 0; g < 2; g++) {
    transpose_conv<float><<<dim3(96, 24, 1), dim3(32, 8), 0, stream>>>(
        exp_w[g], wgt1 + g * sW1, 768, 3072, 0, 0);
    transpose_conv<float><<<dim3(24, 96, 1), dim3(32, 8), 0, stream>>>(
        col_w[g], wgt2 + g * sW2, 3072, 768, 0, 0);
  }
  // G = relu(adj @ T2)   [1024,1024]@[1024,768] x16 -> bufB2   [SWZ=1]
  gemm256<1, 1><<<192, 512, 0, stream>>>(
      adj2, 1LL << 20, bufA2, 768LL * 8192, 1024, 8192, bufB2, sNM, 768,
      nullptr, nullptr, 1024);
  // U = gelu(G @ expW + b)   [8192,768]@[768,3072] x2 -> X12 (X1 dead)
  gemm256<2, 0><<<dim3(32, 12, 2), 512, 0, stream>>>(
      bufB2, 8192LL * 768, wgt1, 0, sW1, 768, X12, sBig, 3072,
      exp_b[0], exp_b[1], 768);
  // V = U @ colW   [8192,3072]@[3072,768] x2 -> bufA2 (T2^T dead)
  gemm256<0, 0><<<dim3(32, 3, 2), 512, 0, stream>>>(
      X12, sBig, wgt2, 0, sW2, 3072, bufA2, 8192LL * 768, 768,
      nullptr, nullptr, 3072);
  // LN(nodes + V + col_b) both graphs -> Gcat (adj2 dead)
  ln_residual2<<<16384, 256, 0, stream>>>(
      nodes, bufA2, col_b[0], col_b[1], ln_g[0], ln_g[1], ln_b[0], ln_b[1], Gcat);
  // out = sigmoid(Gcat @ WeffT^T + gate_b) blend -> fused gate epilogue
  gemm_bt<3, 0, 0, 1><<<dim3(64, 6, 1), 256, 0, stream>>>(
      Gcat, 0, wefft, 0, 0, 1536, out, 0, 768,
      gate_b, nullptr, Gcat, 1536);
}